// Round 12
// baseline (1792.302 us; speedup 1.0000x reference)
//
#include <hip/hip_runtime.h>
#include <hip/hip_bf16.h>
#include <math.h>

#define B 256
#define S 128
#define I_DIM 512
#define H 1024
#define C 10
#define WROW 1536

#define LDS_H 131072                 // 64 b-rows x 1024 k bf16, XOR-swizzled

typedef float f32x4 __attribute__((ext_vector_type(4), may_alias));
typedef float f32x16 __attribute__((ext_vector_type(16), may_alias));
typedef __bf16 bf16x8 __attribute__((ext_vector_type(8), may_alias));
typedef unsigned int u32x4 __attribute__((ext_vector_type(4), may_alias));
typedef unsigned long long u64;
typedef unsigned long long __attribute__((may_alias)) u64a;

__device__ __forceinline__ unsigned short f2bf(float f) {
    union { float f; unsigned u; } a; a.f = f;
    return (unsigned short)((a.u + 0x7fffu + ((a.u >> 16) & 1u)) >> 16);
}
__device__ __forceinline__ float bf2f(unsigned short b) {
    union { unsigned u; float f; } a; a.u = ((unsigned)b) << 16;
    return a.f;
}
__device__ __forceinline__ float sigf(float v) { return 1.0f / (1.0f + __expf(-v)); }
__device__ __forceinline__ float tanh_fast(float v) { return 1.0f - 2.0f / (1.0f + __expf(2.0f * v)); }

// ---- prep 1a: recurrent W -> bf16 32x32x16-fragment stream (k = 512..1535) ----
// wF[(((d*128+nsub)*64+kstep)*64+lane)*8+e] = W_d[g*1024+j][512 + kstep*16 + (lane>>5)*8 + e]
//   n_gl = nsub*32 + (lane&31), j = n_gl>>2, g = n_gl&3  (gate-interleaved rows)
__global__ void wf_build32(const float* __restrict__ fwd_W,
                           const float* __restrict__ bwd_W,
                           __hip_bfloat16* __restrict__ wF) {
    int gid = blockIdx.x * 256 + threadIdx.x;   // 2*128*64*64 = 1,048,576
    int lane = gid & 63, kstep = (gid >> 6) & 63, nsub = (gid >> 12) & 127, d = gid >> 19;
    int n_gl = nsub * 32 + (lane & 31);
    int j = n_gl >> 2, g = n_gl & 3;
    int k = kstep * 16 + (lane >> 5) * 8;
    const float* W = d ? bwd_W : fwd_W;
    const float* src = W + (size_t)(g * 1024 + j) * WROW + I_DIM + k;
    ushort4 lo = make_ushort4(f2bf(src[0]), f2bf(src[1]), f2bf(src[2]), f2bf(src[3]));
    ushort4 hi = make_ushort4(f2bf(src[4]), f2bf(src[5]), f2bf(src[6]), f2bf(src[7]));
    ushort4* dst = (ushort4*)(wF + (size_t)gid * 8);
    dst[0] = lo; dst[1] = hi;
}

// ---- prep 1b: input-projection W -> bf16 16x16x32 fragment stream (k = 0..511) ----
__global__ void wxf_build(const float* __restrict__ fwd_W,
                          const float* __restrict__ bwd_W,
                          __hip_bfloat16* __restrict__ wxF) {
    int gid = blockIdx.x * 256 + threadIdx.x;   // 2*256*16*64 = 524288
    int lane = gid & 63, kk = (gid >> 6) & 15, nsub = (gid >> 10) & 255, d = gid >> 18;
    int n_gl = nsub * 16 + (lane & 15);
    int j = n_gl >> 2, g = n_gl & 3;
    int k = kk * 32 + (lane >> 4) * 8;
    const float* W = d ? bwd_W : fwd_W;
    const float* src = W + (size_t)(g * 1024 + j) * WROW + k;
    ushort4 lo = make_ushort4(f2bf(src[0]), f2bf(src[1]), f2bf(src[2]), f2bf(src[3]));
    ushort4 hi = make_ushort4(f2bf(src[4]), f2bf(src[5]), f2bf(src[6]), f2bf(src[7]));
    ushort4* dst = (ushort4*)(wxF + (size_t)gid * 8);
    dst[0] = lo; dst[1] = hi;
}

// ---- prep 1c: embed -> split bf16 (hi + lo, exact to 2^-17) ----
__global__ void ehl_build(const float* __restrict__ embed,
                          unsigned short* __restrict__ ehl) {
    int idx = blockIdx.x * 256 + threadIdx.x;   // 65536
    float e = embed[idx];
    unsigned short hb = f2bf(e);
    unsigned short lb = f2bf(e - bf2f(hb));
    ehl[idx] = hb;
    ehl[65536 + idx] = lb;
}

// ---- prep 2: projP[d][j][v][g] via split-bf16 MFMA (verified r10/r11) ----
__global__ __launch_bounds__(256) void projp_mfma(
        const __hip_bfloat16* __restrict__ wxF,
        const unsigned short* __restrict__ ehl,
        const float* __restrict__ fwd_b,
        const float* __restrict__ bwd_b,
        float* __restrict__ projP) {
    extern __shared__ char sm[];
    const int bid = blockIdx.x;
    const int d = bid >> 7, jt = (bid >> 2) & 31, vb = bid & 3;
    const int tid = threadIdx.x, w = tid >> 6, lane = tid & 63;
    const int l15 = lane & 15, l4 = lane >> 4;
    const int v0 = vb * 32;

    for (int i = 0; i < 16; i++) {
        int chunk = i * 256 + tid;
        int row = chunk >> 6, c16 = chunk & 63;
        int p = row >> 5, vs = v0 + (row & 31);
        u32x4 vd = *(const u32x4*)(ehl + ((size_t)p * 128 + vs) * 512 + c16 * 8);
        *(u32x4*)(sm + row * 1024 + ((c16 * 16) ^ ((row & 7) << 4))) = vd;
    }
    __syncthreads();

    const __hip_bfloat16* ap0 = wxF + ((size_t)((d * 256 + jt * 8 + w * 2 + 0) * 16)) * 512;
    const __hip_bfloat16* ap1 = wxF + ((size_t)((d * 256 + jt * 8 + w * 2 + 1) * 16)) * 512;
    int hrow[2], hswz[2], lrow[2], lswz[2];
#pragma unroll
    for (int vt = 0; vt < 2; vt++) {
        int hr = vt * 16 + l15, lr = hr + 32;
        hrow[vt] = hr * 1024; hswz[vt] = (hr & 7) << 4;
        lrow[vt] = lr * 1024; lswz[vt] = (lr & 7) << 4;
    }
    f32x4 acc[2][2] = {};
#pragma unroll
    for (int kk = 0; kk < 16; kk++) {
        bf16x8 A0 = *(const bf16x8*)(ap0 + kk * 512 + lane * 8);
        bf16x8 A1 = *(const bf16x8*)(ap1 + kk * 512 + lane * 8);
        int ko = kk * 64 + l4 * 16;
        bf16x8 Bh0 = *(const bf16x8*)(sm + hrow[0] + (ko ^ hswz[0]));
        bf16x8 Bh1 = *(const bf16x8*)(sm + hrow[1] + (ko ^ hswz[1]));
        bf16x8 Bl0 = *(const bf16x8*)(sm + lrow[0] + (ko ^ lswz[0]));
        bf16x8 Bl1 = *(const bf16x8*)(sm + lrow[1] + (ko ^ lswz[1]));
        acc[0][0] = __builtin_amdgcn_mfma_f32_16x16x32_bf16(A0, Bh0, acc[0][0], 0, 0, 0);
        acc[0][0] = __builtin_amdgcn_mfma_f32_16x16x32_bf16(A0, Bl0, acc[0][0], 0, 0, 0);
        acc[0][1] = __builtin_amdgcn_mfma_f32_16x16x32_bf16(A0, Bh1, acc[0][1], 0, 0, 0);
        acc[0][1] = __builtin_amdgcn_mfma_f32_16x16x32_bf16(A0, Bl1, acc[0][1], 0, 0, 0);
        acc[1][0] = __builtin_amdgcn_mfma_f32_16x16x32_bf16(A1, Bh0, acc[1][0], 0, 0, 0);
        acc[1][0] = __builtin_amdgcn_mfma_f32_16x16x32_bf16(A1, Bl0, acc[1][0], 0, 0, 0);
        acc[1][1] = __builtin_amdgcn_mfma_f32_16x16x32_bf16(A1, Bh1, acc[1][1], 0, 0, 0);
        acc[1][1] = __builtin_amdgcn_mfma_f32_16x16x32_bf16(A1, Bl1, acc[1][1], 0, 0, 0);
    }
    const float* bp = d ? bwd_b : fwd_b;
#pragma unroll
    for (int nt = 0; nt < 2; nt++) {
        int j = jt * 32 + w * 8 + nt * 4 + l4;
        f32x4 bv = { bp[j], bp[1024 + j], bp[2048 + j], bp[3072 + j] };
#pragma unroll
        for (int vt = 0; vt < 2; vt++) {
            int v = v0 + vt * 16 + l15;
            *(f32x4*)(projP + ((size_t)(d * 1024 + j) * 128 + v) * 4) = acc[nt][vt] + bv;
        }
    }
}

// ---- fused per-step kernel: 32x32x16 MFMA, one tile per wave ----
// grid 256 x 512thr. block=(d, bt, jt): 64 b x 32 j (128 gate-interleaved n).
// 8 waves = 4 ngrp x 2 bgrp; wave owns 32n x 32b = ONE 32x32 MFMA tile.
// k-loop: 64 steps of k16; per step 1 A-read (L2 stream) + 1 B-read (LDS) + 1 MFMA.
// C layout (HW-verified): col=lane&31 (b), row=(reg&3)+8*(reg>>2)+4*(lane>>5):
//   gate = reg&3, j_local = 2*(reg>>2) + (lane>>5)  -> 4 gates of (b, j) per lane.
__global__ __launch_bounds__(512, 1) void step_kernel(
        const int* __restrict__ x,
        const __hip_bfloat16* __restrict__ wF,
        const float* __restrict__ projP,
        __hip_bfloat16* __restrict__ hbuf,   // [2 parity][2 d][256 b][1024 j]
        float* __restrict__ cws,             // [256 blk][512 tid][4]
        int t) {
    extern __shared__ char smem[];
    const int bid = blockIdx.x;
    const int d = bid >> 7, bt = (bid >> 5) & 3, jt = bid & 31;
    const int tid = threadIdx.x, wid = tid >> 6, lane = tid & 63;
    const int ngrp = wid >> 1, bgrp = wid & 1;
    const int l31 = lane & 31, l32 = lane >> 5;
    const int b0 = bt * 64;
    const size_t dBH = (size_t)d * B * H;

    const __hip_bfloat16* wp = wF + (size_t)(d * 128 + jt * 4 + ngrp) * 32768;

    // ---- issue A-ring preload + x gather before staging (latency overlap) ----
    bf16x8 Ap[8];
    if (t > 0) {
#pragma unroll
        for (int p = 0; p < 8; p++)
            Ap[p] = *(const bf16x8*)(wp + p * 512 + lane * 8);
    }
    const int tt = d ? (S - 1 - t) : t;
    const int bg = b0 + bgrp * 32 + l31;          // this lane's batch row
    const int vv = x[bg * S + tt];

    float* cp = cws + ((size_t)bid * 512 + tid) * 4;
    f32x4 cv = {0.f, 0.f, 0.f, 0.f};
    if (t > 0) cv = *(const f32x4*)cp;

    // stage h[d][b0..b0+64][*] into LDS (bf16, XOR-swizzled rows) — r6 pattern
    if (t > 0) {
        const __hip_bfloat16* hr = hbuf + (size_t)(t & 1) * 2 * B * H + dBH + (size_t)b0 * H;
#pragma unroll
        for (int i = 0; i < 16; i++) {
            int flat = i * 512 + tid;        // row = flat>>7, c16 = flat&127
            int row = flat >> 7, c16 = flat & 127;
            u32x4 v = *(const u32x4*)(hr + (size_t)row * H + c16 * 8);
            *(u32x4*)(smem + row * 2048 + ((c16 * 16) ^ ((row & 7) << 4))) = v;
        }
    }

    // proj gather: lane needs 4 j values (j_local = 2p + l32), one b (vv)
    f32x4 pj[4];
#pragma unroll
    for (int p = 0; p < 4; p++) {
        int j = jt * 32 + ngrp * 8 + 2 * p + l32;
        pj[p] = *((const f32x4*)projP + ((size_t)(d * 1024 + j) * 128 + vv));
    }

    f32x16 acc = {};
    if (t > 0) {
        __syncthreads();
        const int brow = (bgrp * 32 + l31) * 2048;
        const int bswz = (l31 & 7) << 4;
        bf16x8 Bp[4];
#pragma unroll
        for (int p = 0; p < 4; p++)
            Bp[p] = *(const bf16x8*)(smem + brow + ((p * 32 + l32 * 16) ^ bswz));
#pragma unroll
        for (int kk = 0; kk < 64; kk++) {
            bf16x8 A = Ap[kk & 7];
            bf16x8 Bv = Bp[kk & 3];
            if (kk < 56)
                Ap[kk & 7] = *(const bf16x8*)(wp + (kk + 8) * 512 + lane * 8);
            if (kk < 60)
                Bp[kk & 3] = *(const bf16x8*)(smem + brow + (((kk + 4) * 32 + l32 * 16) ^ bswz));
            acc = __builtin_amdgcn_mfma_f32_32x32x16_bf16(A, Bv, acc, 0, 0, 0);
        }
    }

    // gates: acc[4p+g] = gate g of (b = bg, j = jt*32 + ngrp*8 + 2p + l32)
    float hnv[4];
#pragma unroll
    for (int p = 0; p < 4; p++) {
        float zg = acc[4 * p + 0] + pj[p][0];
        float zi = acc[4 * p + 1] + pj[p][1];
        float zf = acc[4 * p + 2] + pj[p][2];
        float zo = acc[4 * p + 3] + pj[p][3];
        float gg = tanh_fast(zg);
        float ii = sigf(zi);
        float ff = sigf(zf);
        float oo = sigf(zo);
        float cn = gg * ii + cv[p] * ff;
        cv[p] = cn;
        hnv[p] = tanh_fast(cn) * oo;
    }
    *(f32x4*)cp = cv;

    // lane<->lane+32 interleave: own j {2p+l32}, partner j {2p+(1-l32)} -> 8B contiguous
    unsigned w0 = (unsigned)f2bf(hnv[0]) | ((unsigned)f2bf(hnv[1]) << 16);  // j_local {0,2}+l32
    unsigned w1 = (unsigned)f2bf(hnv[2]) | ((unsigned)f2bf(hnv[3]) << 16);  // j_local {4,6}+l32
    unsigned pw0 = __shfl(w0, lane ^ 32);
    unsigned pw1 = __shfl(w1, lane ^ 32);
    unsigned a  = l32 ? pw1 : w0;    // even-j pair for this lane's half
    unsigned b2 = l32 ? w1 : pw0;    // odd-j pair
    u64 hv = (u64)(a & 0xffffu) | ((u64)(b2 & 0xffffu) << 16)
           | ((u64)(a >> 16) << 32) | ((u64)(b2 >> 16) << 48);
    __hip_bfloat16* hw = hbuf + (size_t)((t + 1) & 1) * 2 * B * H + dBH
                         + (size_t)bg * H + jt * 32 + ngrp * 8 + l32 * 4;
    *(u64a*)hw = hv;
}

// ---- head: logits + log_softmax (reads bf16 h, parity 0) ----
__global__ void head_kernel(const __hip_bfloat16* __restrict__ hbuf,
                            const float* __restrict__ p_w,
                            const float* __restrict__ p_b,
                            float* __restrict__ out) {
    int b = blockIdx.x;
    int lane = threadIdx.x;  // 64
    float part[C];
#pragma unroll
    for (int cc = 0; cc < C; cc++) part[cc] = 0.0f;
    for (int jj = lane; jj < 2 * H; jj += 64) {
        float hv = (jj < H)
            ? __bfloat162float(hbuf[(size_t)b * H + jj])
            : __bfloat162float(hbuf[(size_t)B * H + (size_t)b * H + jj - H]);
#pragma unroll
        for (int cc = 0; cc < C; cc++) part[cc] += hv * p_w[cc * 2 * H + jj];
    }
#pragma unroll
    for (int cc = 0; cc < C; cc++) {
        float v = part[cc];
        for (int off = 32; off; off >>= 1) v += __shfl_down(v, off);
        part[cc] = v;
    }
    if (lane == 0) {
        float lg[C];
        float m = -1e30f;
        for (int cc = 0; cc < C; cc++) {
            lg[cc] = part[cc] + p_b[cc];
            m = fmaxf(m, lg[cc]);
        }
        float s = 0.0f;
        for (int cc = 0; cc < C; cc++) s += expf(lg[cc] - m);
        float lse = logf(s) + m;
        for (int cc = 0; cc < C; cc++) out[b * C + cc] = lg[cc] - lse;
    }
}

extern "C" void kernel_launch(void* const* d_in, const int* in_sizes, int n_in,
                              void* d_out, int out_size, void* d_ws, size_t ws_size,
                              hipStream_t stream) {
    const int*   x     = (const int*)d_in[0];
    const float* embed = (const float*)d_in[1];
    const float* fwd_W = (const float*)d_in[2];
    const float* fwd_b = (const float*)d_in[3];
    const float* bwd_W = (const float*)d_in[4];
    const float* bwd_b = (const float*)d_in[5];
    const float* p_w   = (const float*)d_in[6];
    const float* p_b   = (const float*)d_in[7];
    float* outp = (float*)d_out;

    char* ws = (char*)d_ws;
    __hip_bfloat16* wF  = (__hip_bfloat16*)ws;  ws += (size_t)2 * 128 * 64 * 64 * 8 * 2; // 16 MB
    // 8 MB region shared in time: wxF (prep only) overlays cws (steps only)
    __hip_bfloat16* wxF = (__hip_bfloat16*)ws;
    float* cws = (float*)ws;                    ws += (size_t)2 * 256 * 8192 * 2;        // 8 MB
    unsigned short* ehl = (unsigned short*)ws;  ws += (size_t)2 * 128 * 512 * 2;         // 256 KB
    float* projP = (float*)ws;                  ws += (size_t)2 * 1024 * 128 * 4 * 4;    // 4 MB
    __hip_bfloat16* hbuf = (__hip_bfloat16*)ws; ws += (size_t)2 * 2 * B * H * 2;         // 2 MB

    hipLaunchKernelGGL(wf_build32, dim3(4096), dim3(256), 0, stream, fwd_W, bwd_W, wF);
    hipLaunchKernelGGL(wxf_build, dim3(2048), dim3(256), 0, stream, fwd_W, bwd_W, wxF);
    hipLaunchKernelGGL(ehl_build, dim3(256), dim3(256), 0, stream, embed, ehl);

    hipFuncSetAttribute((const void*)projp_mfma,
                        hipFuncAttributeMaxDynamicSharedMemorySize, 65536);
    hipLaunchKernelGGL(projp_mfma, dim3(256), dim3(256), 65536, stream,
                       wxF, ehl, fwd_b, bwd_b, projP);

    hipFuncSetAttribute((const void*)step_kernel,
                        hipFuncAttributeMaxDynamicSharedMemorySize, LDS_H);
    for (int t = 0; t < S; t++)
        hipLaunchKernelGGL(step_kernel, dim3(256), dim3(512), LDS_H, stream,
                           x, wF, projP, hbuf, cws, t);

    hipLaunchKernelGGL(head_kernel, dim3(B), dim3(64), 0, stream,
                       hbuf, p_w, p_b, outp);
}

// Round 13
// 1431.312 us; speedup vs baseline: 1.2522x; 1.2522x over previous
//
#include <hip/hip_runtime.h>
#include <hip/hip_bf16.h>
#include <math.h>

#define B 256
#define S 128
#define I_DIM 512
#define H 1024
#define C 10
#define WROW 1536

#define LDS_H 131072                 // 64 b-rows x 1024 k bf16, XOR-swizzled

typedef float f32x4 __attribute__((ext_vector_type(4), may_alias));
typedef __bf16 bf16x8 __attribute__((ext_vector_type(8), may_alias));
typedef unsigned int u32x4 __attribute__((ext_vector_type(4), may_alias));
typedef unsigned long long u64;
typedef unsigned long long __attribute__((may_alias)) u64a;

__device__ __forceinline__ unsigned short f2bf(float f) {
    union { float f; unsigned u; } a; a.f = f;
    return (unsigned short)((a.u + 0x7fffu + ((a.u >> 16) & 1u)) >> 16);
}
__device__ __forceinline__ float bf2f(unsigned short b) {
    union { unsigned u; float f; } a; a.u = ((unsigned)b) << 16;
    return a.f;
}
__device__ __forceinline__ float sigf(float v) { return 1.0f / (1.0f + __expf(-v)); }
__device__ __forceinline__ float tanh_fast(float v) { return 1.0f - 2.0f / (1.0f + __expf(2.0f * v)); }

// ---- prep 1a: recurrent W -> bf16 16x16x32-fragment stream (k = 512..1535) ----
// wF[(((d*256+nsub)*32+kk)*64+lane)*8+e] = W_d[g*1024+j][512 + kk*32 + (lane>>4)*8 + e]
//   n_gl = nsub*16 + (lane&15), j = n_gl>>2, g = n_gl&3  (gate-interleaved)
__global__ void wf_build(const float* __restrict__ fwd_W,
                         const float* __restrict__ bwd_W,
                         __hip_bfloat16* __restrict__ wF) {
    int gid = blockIdx.x * 256 + threadIdx.x;   // 2*256*32*64
    int lane = gid & 63, kk = (gid >> 6) & 31, nsub = (gid >> 11) & 255, d = gid >> 19;
    int n_gl = nsub * 16 + (lane & 15);
    int j = n_gl >> 2, g = n_gl & 3;
    int k = kk * 32 + (lane >> 4) * 8;
    const float* W = d ? bwd_W : fwd_W;
    const float* src = W + (size_t)(g * 1024 + j) * WROW + I_DIM + k;
    ushort4 lo = make_ushort4(f2bf(src[0]), f2bf(src[1]), f2bf(src[2]), f2bf(src[3]));
    ushort4 hi = make_ushort4(f2bf(src[4]), f2bf(src[5]), f2bf(src[6]), f2bf(src[7]));
    ushort4* dst = (ushort4*)(wF + (size_t)gid * 8);
    dst[0] = lo; dst[1] = hi;
}

// ---- prep 1b: input-projection W -> bf16 fragment stream (k = 0..511) ----
__global__ void wxf_build(const float* __restrict__ fwd_W,
                          const float* __restrict__ bwd_W,
                          __hip_bfloat16* __restrict__ wxF) {
    int gid = blockIdx.x * 256 + threadIdx.x;   // 2*256*16*64 = 524288
    int lane = gid & 63, kk = (gid >> 6) & 15, nsub = (gid >> 10) & 255, d = gid >> 18;
    int n_gl = nsub * 16 + (lane & 15);
    int j = n_gl >> 2, g = n_gl & 3;
    int k = kk * 32 + (lane >> 4) * 8;
    const float* W = d ? bwd_W : fwd_W;
    const float* src = W + (size_t)(g * 1024 + j) * WROW + k;
    ushort4 lo = make_ushort4(f2bf(src[0]), f2bf(src[1]), f2bf(src[2]), f2bf(src[3]));
    ushort4 hi = make_ushort4(f2bf(src[4]), f2bf(src[5]), f2bf(src[6]), f2bf(src[7]));
    ushort4* dst = (ushort4*)(wxF + (size_t)gid * 8);
    dst[0] = lo; dst[1] = hi;
}

// ---- prep 1c: embed -> split bf16 (hi + lo, exact to 2^-17) ----
__global__ void ehl_build(const float* __restrict__ embed,
                          unsigned short* __restrict__ ehl) {
    int idx = blockIdx.x * 256 + threadIdx.x;   // 65536
    float e = embed[idx];
    unsigned short hb = f2bf(e);
    unsigned short lb = f2bf(e - bf2f(hb));
    ehl[idx] = hb;
    ehl[65536 + idx] = lb;
}

// ---- prep 2: projP[d][j][v][g] via split-bf16 MFMA (verified r10-r12) ----
__global__ __launch_bounds__(256) void projp_mfma(
        const __hip_bfloat16* __restrict__ wxF,
        const unsigned short* __restrict__ ehl,
        const float* __restrict__ fwd_b,
        const float* __restrict__ bwd_b,
        float* __restrict__ projP) {
    extern __shared__ char sm[];
    const int bid = blockIdx.x;
    const int d = bid >> 7, jt = (bid >> 2) & 31, vb = bid & 3;
    const int tid = threadIdx.x, w = tid >> 6, lane = tid & 63;
    const int l15 = lane & 15, l4 = lane >> 4;
    const int v0 = vb * 32;

    for (int i = 0; i < 16; i++) {
        int chunk = i * 256 + tid;
        int row = chunk >> 6, c16 = chunk & 63;
        int p = row >> 5, vs = v0 + (row & 31);
        u32x4 vd = *(const u32x4*)(ehl + ((size_t)p * 128 + vs) * 512 + c16 * 8);
        *(u32x4*)(sm + row * 1024 + ((c16 * 16) ^ ((row & 7) << 4))) = vd;
    }
    __syncthreads();

    const __hip_bfloat16* ap0 = wxF + ((size_t)((d * 256 + jt * 8 + w * 2 + 0) * 16)) * 512;
    const __hip_bfloat16* ap1 = wxF + ((size_t)((d * 256 + jt * 8 + w * 2 + 1) * 16)) * 512;
    int hrow[2], hswz[2], lrow[2], lswz[2];
#pragma unroll
    for (int vt = 0; vt < 2; vt++) {
        int hr = vt * 16 + l15, lr = hr + 32;
        hrow[vt] = hr * 1024; hswz[vt] = (hr & 7) << 4;
        lrow[vt] = lr * 1024; lswz[vt] = (lr & 7) << 4;
    }
    f32x4 acc[2][2] = {};
#pragma unroll
    for (int kk = 0; kk < 16; kk++) {
        bf16x8 A0 = *(const bf16x8*)(ap0 + kk * 512 + lane * 8);
        bf16x8 A1 = *(const bf16x8*)(ap1 + kk * 512 + lane * 8);
        int ko = kk * 64 + l4 * 16;
        bf16x8 Bh0 = *(const bf16x8*)(sm + hrow[0] + (ko ^ hswz[0]));
        bf16x8 Bh1 = *(const bf16x8*)(sm + hrow[1] + (ko ^ hswz[1]));
        bf16x8 Bl0 = *(const bf16x8*)(sm + lrow[0] + (ko ^ lswz[0]));
        bf16x8 Bl1 = *(const bf16x8*)(sm + lrow[1] + (ko ^ lswz[1]));
        acc[0][0] = __builtin_amdgcn_mfma_f32_16x16x32_bf16(A0, Bh0, acc[0][0], 0, 0, 0);
        acc[0][0] = __builtin_amdgcn_mfma_f32_16x16x32_bf16(A0, Bl0, acc[0][0], 0, 0, 0);
        acc[0][1] = __builtin_amdgcn_mfma_f32_16x16x32_bf16(A0, Bh1, acc[0][1], 0, 0, 0);
        acc[0][1] = __builtin_amdgcn_mfma_f32_16x16x32_bf16(A0, Bl1, acc[0][1], 0, 0, 0);
        acc[1][0] = __builtin_amdgcn_mfma_f32_16x16x32_bf16(A1, Bh0, acc[1][0], 0, 0, 0);
        acc[1][0] = __builtin_amdgcn_mfma_f32_16x16x32_bf16(A1, Bl0, acc[1][0], 0, 0, 0);
        acc[1][1] = __builtin_amdgcn_mfma_f32_16x16x32_bf16(A1, Bh1, acc[1][1], 0, 0, 0);
        acc[1][1] = __builtin_amdgcn_mfma_f32_16x16x32_bf16(A1, Bl1, acc[1][1], 0, 0, 0);
    }
    const float* bp = d ? bwd_b : fwd_b;
#pragma unroll
    for (int nt = 0; nt < 2; nt++) {
        int j = jt * 32 + w * 8 + nt * 4 + l4;
        f32x4 bv = { bp[j], bp[1024 + j], bp[2048 + j], bp[3072 + j] };
#pragma unroll
        for (int vt = 0; vt < 2; vt++) {
            int v = v0 + vt * 16 + l15;
            *(f32x4*)(projP + ((size_t)(d * 1024 + j) * 128 + v) * 4) = acc[nt][vt] + bv;
        }
    }
}

// ---- fused per-step kernel: EXACT round-6 version (measured 10.8 us/step) ----
// grid 256 x 512thr. block=(d, bt, jt): 64 b x 32 j (128 gate-interleaved n).
// 8 waves: wave wid owns j = jt*32 + wid*4 + l4 (16 n) x 64 b.
// A = W-frag streamed from wF (global, unique), B = h-frag from swizzled LDS.
// C layout (HW-verified): col(l15)=b, row(l4*4+reg): j-sub=l4, gate=reg.
__global__ __launch_bounds__(512, 1) void step_kernel(
        const int* __restrict__ x,
        const __hip_bfloat16* __restrict__ wF,
        const float* __restrict__ projP,
        __hip_bfloat16* __restrict__ hbuf,   // [2 parity][2 d][256 b][1024 j]
        float* __restrict__ cws,             // [256 blk][512 tid][4]
        int t) {
    extern __shared__ char smem[];
    const int bid = blockIdx.x;
    const int d = bid >> 7, bt = (bid >> 5) & 3, jt = bid & 31;
    const int tid = threadIdx.x, wid = tid >> 6, lane = tid & 63;
    const int l15 = lane & 15, l4 = lane >> 4;
    const int b0 = bt * 64;
    const size_t dBH = (size_t)d * B * H;

    // stage h[d][b0..b0+64][0..1024] into LDS (bf16, XOR-swizzled rows)
    if (t > 0) {
        const __hip_bfloat16* hr = hbuf + (size_t)(t & 1) * 2 * B * H + dBH + (size_t)b0 * H;
#pragma unroll
        for (int i = 0; i < 16; i++) {
            int flat = i * 512 + tid;        // 16B chunk: row = flat>>7, c16 = flat&127
            int row = flat >> 7, c16 = flat & 127;
            u32x4 v = *(const u32x4*)(hr + (size_t)row * H + c16 * 8);
            *(u32x4*)(smem + row * 2048 + ((c16 * 16) ^ ((row & 7) << 4))) = v;
        }
        __syncthreads();
    }

    f32x4 acc[4] = {};
    if (t > 0) {
        const __hip_bfloat16* wp = wF + (size_t)(d * 256 + jt * 8 + wid) * 16384;
        int brow[4], bswz[4];
#pragma unroll
        for (int bs = 0; bs < 4; bs++) {
            int row = bs * 16 + l15;
            brow[bs] = row * 2048;
            bswz[bs] = (row & 7) << 4;
        }
        bf16x8 Acur = *(const bf16x8*)(wp + lane * 8);
        bf16x8 Bcur[4];
#pragma unroll
        for (int bs = 0; bs < 4; bs++)
            Bcur[bs] = *(const bf16x8*)(smem + brow[bs] + ((l4 * 16) ^ bswz[bs]));
#pragma unroll
        for (int kk = 0; kk < 32; kk++) {
            bf16x8 A = Acur;
            bf16x8 B0 = Bcur[0], B1 = Bcur[1], B2 = Bcur[2], B3 = Bcur[3];
            if (kk < 31) {
                Acur = *(const bf16x8*)(wp + (kk + 1) * 512 + lane * 8);
                int koff = (kk + 1) * 64 + l4 * 16;
#pragma unroll
                for (int bs = 0; bs < 4; bs++)
                    Bcur[bs] = *(const bf16x8*)(smem + brow[bs] + (koff ^ bswz[bs]));
            }
            acc[0] = __builtin_amdgcn_mfma_f32_16x16x32_bf16(A, B0, acc[0], 0, 0, 0);
            acc[1] = __builtin_amdgcn_mfma_f32_16x16x32_bf16(A, B1, acc[1], 0, 0, 0);
            acc[2] = __builtin_amdgcn_mfma_f32_16x16x32_bf16(A, B2, acc[2], 0, 0, 0);
            acc[3] = __builtin_amdgcn_mfma_f32_16x16x32_bf16(A, B3, acc[3], 0, 0, 0);
        }
    }

    // proj gather for this step
    const int tt = d ? (S - 1 - t) : t;
    const int j = jt * 32 + wid * 4 + l4;
    const f32x4* pp = (const f32x4*)projP + ((size_t)d * 1024 + j) * 128;
    f32x4 pj[4];
#pragma unroll
    for (int bs = 0; bs < 4; bs++) {
        int v = x[(b0 + bs * 16 + l15) * S + tt];
        pj[bs] = pp[v];
    }

    float* cp = cws + ((size_t)bid * 512 + tid) * 4;
    f32x4 cv = {0.f, 0.f, 0.f, 0.f};
    if (t > 0) cv = *(const f32x4*)cp;

    float hnv[4];
#pragma unroll
    for (int bs = 0; bs < 4; bs++) {
        float zg = acc[bs][0] + pj[bs][0];
        float zi = acc[bs][1] + pj[bs][1];
        float zf = acc[bs][2] + pj[bs][2];
        float zo = acc[bs][3] + pj[bs][3];
        float gg = tanh_fast(zg);
        float ii = sigf(zi);
        float ff = sigf(zf);
        float oo = sigf(zo);
        float cn = gg * ii + cv[bs] * ff;
        cv[bs] = cn;
        hnv[bs] = tanh_fast(cn) * oo;
    }
    *(f32x4*)cp = cv;

    // pure-register wave transpose via shfl (verified r6-r8 pattern)
    unsigned plo = (unsigned)f2bf(hnv[0]) | ((unsigned)f2bf(hnv[1]) << 16);
    unsigned phi = (unsigned)f2bf(hnv[2]) | ((unsigned)f2bf(hnv[3]) << 16);
    unsigned short o4[4];
#pragma unroll
    for (int p = 0; p < 4; p++) {
        int src = p * 16 + l15;
        unsigned vlo = __shfl(plo, src);
        unsigned vhi = __shfl(phi, src);
        unsigned sel = (l4 < 2) ? vlo : vhi;
        o4[p] = (l4 & 1) ? (unsigned short)(sel >> 16) : (unsigned short)(sel & 0xffffu);
    }
    u64 hv = (u64)o4[0] | ((u64)o4[1] << 16) | ((u64)o4[2] << 32) | ((u64)o4[3] << 48);
    __hip_bfloat16* hw = hbuf + (size_t)((t + 1) & 1) * 2 * B * H + dBH
                         + (size_t)(b0 + lane) * H + jt * 32 + wid * 4;
    *(u64a*)hw = hv;
}

// ---- head: logits + log_softmax (reads bf16 h, parity 0) ----
__global__ void head_kernel(const __hip_bfloat16* __restrict__ hbuf,
                            const float* __restrict__ p_w,
                            const float* __restrict__ p_b,
                            float* __restrict__ out) {
    int b = blockIdx.x;
    int lane = threadIdx.x;  // 64
    float part[C];
#pragma unroll
    for (int cc = 0; cc < C; cc++) part[cc] = 0.0f;
    for (int jj = lane; jj < 2 * H; jj += 64) {
        float hv = (jj < H)
            ? __bfloat162float(hbuf[(size_t)b * H + jj])
            : __bfloat162float(hbuf[(size_t)B * H + (size_t)b * H + jj - H]);
#pragma unroll
        for (int cc = 0; cc < C; cc++) part[cc] += hv * p_w[cc * 2 * H + jj];
    }
#pragma unroll
    for (int cc = 0; cc < C; cc++) {
        float v = part[cc];
        for (int off = 32; off; off >>= 1) v += __shfl_down(v, off);
        part[cc] = v;
    }
    if (lane == 0) {
        float lg[C];
        float m = -1e30f;
        for (int cc = 0; cc < C; cc++) {
            lg[cc] = part[cc] + p_b[cc];
            m = fmaxf(m, lg[cc]);
        }
        float s = 0.0f;
        for (int cc = 0; cc < C; cc++) s += expf(lg[cc] - m);
        float lse = logf(s) + m;
        for (int cc = 0; cc < C; cc++) out[b * C + cc] = lg[cc] - lse;
    }
}

extern "C" void kernel_launch(void* const* d_in, const int* in_sizes, int n_in,
                              void* d_out, int out_size, void* d_ws, size_t ws_size,
                              hipStream_t stream) {
    const int*   x     = (const int*)d_in[0];
    const float* embed = (const float*)d_in[1];
    const float* fwd_W = (const float*)d_in[2];
    const float* fwd_b = (const float*)d_in[3];
    const float* bwd_W = (const float*)d_in[4];
    const float* bwd_b = (const float*)d_in[5];
    const float* p_w   = (const float*)d_in[6];
    const float* p_b   = (const float*)d_in[7];
    float* outp = (float*)d_out;

    char* ws = (char*)d_ws;
    __hip_bfloat16* wF  = (__hip_bfloat16*)ws;  ws += (size_t)2 * 256 * 16384 * 2;    // 16 MB
    // 8 MB region shared in time: wxF (prep only) overlays cws (steps only)
    __hip_bfloat16* wxF = (__hip_bfloat16*)ws;
    float* cws = (float*)ws;                    ws += (size_t)2 * 256 * 8192 * 2;     // 8 MB
    unsigned short* ehl = (unsigned short*)ws;  ws += (size_t)2 * 128 * 512 * 2;      // 256 KB
    float* projP = (float*)ws;                  ws += (size_t)2 * 1024 * 128 * 4 * 4; // 4 MB
    __hip_bfloat16* hbuf = (__hip_bfloat16*)ws; ws += (size_t)2 * 2 * B * H * 2;      // 2 MB

    hipLaunchKernelGGL(wf_build, dim3(4096), dim3(256), 0, stream, fwd_W, bwd_W, wF);
    hipLaunchKernelGGL(wxf_build, dim3(2048), dim3(256), 0, stream, fwd_W, bwd_W, wxF);
    hipLaunchKernelGGL(ehl_build, dim3(256), dim3(256), 0, stream, embed, ehl);

    hipFuncSetAttribute((const void*)projp_mfma,
                        hipFuncAttributeMaxDynamicSharedMemorySize, 65536);
    hipLaunchKernelGGL(projp_mfma, dim3(256), dim3(256), 65536, stream,
                       wxF, ehl, fwd_b, bwd_b, projP);

    hipFuncSetAttribute((const void*)step_kernel,
                        hipFuncAttributeMaxDynamicSharedMemorySize, LDS_H);
    for (int t = 0; t < S; t++)
        hipLaunchKernelGGL(step_kernel, dim3(256), dim3(512), LDS_H, stream,
                           x, wF, projP, hbuf, cws, t);

    hipLaunchKernelGGL(head_kernel, dim3(B), dim3(64), 0, stream,
                       hbuf, p_w, p_b, outp);
}

// Round 14
// 1415.019 us; speedup vs baseline: 1.2666x; 1.0115x over previous
//
#include <hip/hip_runtime.h>
#include <hip/hip_bf16.h>
#include <math.h>

#define B 256
#define S 128
#define I_DIM 512
#define H 1024
#define C 10
#define WROW 1536

#define LDS_H 131072                 // 64 b-rows x 1024 k bf16, XOR-swizzled

typedef float f32x4 __attribute__((ext_vector_type(4), may_alias));
typedef __bf16 bf16x8 __attribute__((ext_vector_type(8), may_alias));
typedef unsigned int u32x4 __attribute__((ext_vector_type(4), may_alias));
typedef unsigned long long u64;
typedef unsigned long long __attribute__((may_alias)) u64a;

__device__ __forceinline__ unsigned short f2bf(float f) {
    union { float f; unsigned u; } a; a.f = f;
    return (unsigned short)((a.u + 0x7fffu + ((a.u >> 16) & 1u)) >> 16);
}
__device__ __forceinline__ float bf2f(unsigned short b) {
    union { unsigned u; float f; } a; a.u = ((unsigned)b) << 16;
    return a.f;
}
__device__ __forceinline__ float sigf(float v) { return 1.0f / (1.0f + __expf(-v)); }
__device__ __forceinline__ float tanh_fast(float v) { return 1.0f - 2.0f / (1.0f + __expf(2.0f * v)); }

// ---- fused prep: wF (recurrent frag stream) + wxF (input-proj frag stream)
//      + ehl (split-bf16 embed). One kernel, 3 gid regions. ----
__global__ void prep_build(const float* __restrict__ fwd_W,
                           const float* __restrict__ bwd_W,
                           const float* __restrict__ embed,
                           __hip_bfloat16* __restrict__ wF,
                           __hip_bfloat16* __restrict__ wxF,
                           unsigned short* __restrict__ ehl) {
    int gid = blockIdx.x * 256 + threadIdx.x;
    if (gid < 1048576) {
        // wF[(((d*256+nsub)*32+kk)*64+lane)*8+e] = W_d[g*1024+j][512+kk*32+(lane>>4)*8+e]
        int lane = gid & 63, kk = (gid >> 6) & 31, nsub = (gid >> 11) & 255, d = gid >> 19;
        int n_gl = nsub * 16 + (lane & 15);
        int j = n_gl >> 2, g = n_gl & 3;
        int k = kk * 32 + (lane >> 4) * 8;
        const float* W = d ? bwd_W : fwd_W;
        const float* src = W + (size_t)(g * 1024 + j) * WROW + I_DIM + k;
        ushort4 lo = make_ushort4(f2bf(src[0]), f2bf(src[1]), f2bf(src[2]), f2bf(src[3]));
        ushort4 hi = make_ushort4(f2bf(src[4]), f2bf(src[5]), f2bf(src[6]), f2bf(src[7]));
        ushort4* dst = (ushort4*)(wF + (size_t)gid * 8);
        dst[0] = lo; dst[1] = hi;
    } else if (gid < 1048576 + 524288) {
        int g2 = gid - 1048576;
        int lane = g2 & 63, kk = (g2 >> 6) & 15, nsub = (g2 >> 10) & 255, d = g2 >> 18;
        int n_gl = nsub * 16 + (lane & 15);
        int j = n_gl >> 2, g = n_gl & 3;
        int k = kk * 32 + (lane >> 4) * 8;
        const float* W = d ? bwd_W : fwd_W;
        const float* src = W + (size_t)(g * 1024 + j) * WROW + k;
        ushort4 lo = make_ushort4(f2bf(src[0]), f2bf(src[1]), f2bf(src[2]), f2bf(src[3]));
        ushort4 hi = make_ushort4(f2bf(src[4]), f2bf(src[5]), f2bf(src[6]), f2bf(src[7]));
        ushort4* dst = (ushort4*)(wxF + (size_t)g2 * 8);
        dst[0] = lo; dst[1] = hi;
    } else {
        int idx = gid - (1048576 + 524288);   // 0..65535
        float e = embed[idx];
        unsigned short hb = f2bf(e);
        unsigned short lb = f2bf(e - bf2f(hb));
        ehl[idx] = hb;
        ehl[65536 + idx] = lb;
    }
}

// ---- prep 2: projP[d][j][v][g] via split-bf16 MFMA (verified r10-r13) ----
__global__ __launch_bounds__(256) void projp_mfma(
        const __hip_bfloat16* __restrict__ wxF,
        const unsigned short* __restrict__ ehl,
        const float* __restrict__ fwd_b,
        const float* __restrict__ bwd_b,
        float* __restrict__ projP) {
    extern __shared__ char sm[];
    const int bid = blockIdx.x;
    const int d = bid >> 7, jt = (bid >> 2) & 31, vb = bid & 3;
    const int tid = threadIdx.x, w = tid >> 6, lane = tid & 63;
    const int l15 = lane & 15, l4 = lane >> 4;
    const int v0 = vb * 32;

    for (int i = 0; i < 16; i++) {
        int chunk = i * 256 + tid;
        int row = chunk >> 6, c16 = chunk & 63;
        int p = row >> 5, vs = v0 + (row & 31);
        u32x4 vd = *(const u32x4*)(ehl + ((size_t)p * 128 + vs) * 512 + c16 * 8);
        *(u32x4*)(sm + row * 1024 + ((c16 * 16) ^ ((row & 7) << 4))) = vd;
    }
    __syncthreads();

    const __hip_bfloat16* ap0 = wxF + ((size_t)((d * 256 + jt * 8 + w * 2 + 0) * 16)) * 512;
    const __hip_bfloat16* ap1 = wxF + ((size_t)((d * 256 + jt * 8 + w * 2 + 1) * 16)) * 512;
    int hrow[2], hswz[2], lrow[2], lswz[2];
#pragma unroll
    for (int vt = 0; vt < 2; vt++) {
        int hr = vt * 16 + l15, lr = hr + 32;
        hrow[vt] = hr * 1024; hswz[vt] = (hr & 7) << 4;
        lrow[vt] = lr * 1024; lswz[vt] = (lr & 7) << 4;
    }
    f32x4 acc[2][2] = {};
#pragma unroll
    for (int kk = 0; kk < 16; kk++) {
        bf16x8 A0 = *(const bf16x8*)(ap0 + kk * 512 + lane * 8);
        bf16x8 A1 = *(const bf16x8*)(ap1 + kk * 512 + lane * 8);
        int ko = kk * 64 + l4 * 16;
        bf16x8 Bh0 = *(const bf16x8*)(sm + hrow[0] + (ko ^ hswz[0]));
        bf16x8 Bh1 = *(const bf16x8*)(sm + hrow[1] + (ko ^ hswz[1]));
        bf16x8 Bl0 = *(const bf16x8*)(sm + lrow[0] + (ko ^ lswz[0]));
        bf16x8 Bl1 = *(const bf16x8*)(sm + lrow[1] + (ko ^ lswz[1]));
        acc[0][0] = __builtin_amdgcn_mfma_f32_16x16x32_bf16(A0, Bh0, acc[0][0], 0, 0, 0);
        acc[0][0] = __builtin_amdgcn_mfma_f32_16x16x32_bf16(A0, Bl0, acc[0][0], 0, 0, 0);
        acc[0][1] = __builtin_amdgcn_mfma_f32_16x16x32_bf16(A0, Bh1, acc[0][1], 0, 0, 0);
        acc[0][1] = __builtin_amdgcn_mfma_f32_16x16x32_bf16(A0, Bl1, acc[0][1], 0, 0, 0);
        acc[1][0] = __builtin_amdgcn_mfma_f32_16x16x32_bf16(A1, Bh0, acc[1][0], 0, 0, 0);
        acc[1][0] = __builtin_amdgcn_mfma_f32_16x16x32_bf16(A1, Bl0, acc[1][0], 0, 0, 0);
        acc[1][1] = __builtin_amdgcn_mfma_f32_16x16x32_bf16(A1, Bh1, acc[1][1], 0, 0, 0);
        acc[1][1] = __builtin_amdgcn_mfma_f32_16x16x32_bf16(A1, Bl1, acc[1][1], 0, 0, 0);
    }
    const float* bp = d ? bwd_b : fwd_b;
#pragma unroll
    for (int nt = 0; nt < 2; nt++) {
        int j = jt * 32 + w * 8 + nt * 4 + l4;
        f32x4 bv = { bp[j], bp[1024 + j], bp[2048 + j], bp[3072 + j] };
#pragma unroll
        for (int vt = 0; vt < 2; vt++) {
            int v = v0 + vt * 16 + l15;
            *(f32x4*)(projP + ((size_t)(d * 1024 + j) * 128 + v) * 4) = acc[nt][vt] + bv;
        }
    }
}

// ---- fused per-step kernel: r6 GEMM/gates verbatim; staging via global_load_lds ----
// LDS layout identical to r6: LDS[row][m] = global[row][m ^ (row&7)] (16B chunks).
// global_load_lds writes linear (wave-uniform base + lane*16), so the source
// address is pre-swizzled per lane (rule #21 / m173 pattern).
__global__ __launch_bounds__(512, 1) void step_kernel(
        const int* __restrict__ x,
        const __hip_bfloat16* __restrict__ wF,
        const float* __restrict__ projP,
        __hip_bfloat16* __restrict__ hbuf,   // [2 parity][2 d][256 b][1024 j]
        float* __restrict__ cws,             // [256 blk][512 tid][4]
        int t) {
    extern __shared__ char smem[];
    const int bid = blockIdx.x;
    const int d = bid >> 7, bt = (bid >> 5) & 3, jt = bid & 31;
    const int tid = threadIdx.x, wid = tid >> 6, lane = tid & 63;
    const int l15 = lane & 15, l4 = lane >> 4;
    const int b0 = bt * 64;
    const size_t dBH = (size_t)d * B * H;

    // stage h[d][b0..b0+64][0..1024] into LDS (effective XOR-swizzled layout)
    if (t > 0) {
        const char* hrb = (const char*)(hbuf + (size_t)(t & 1) * 2 * B * H + dBH + (size_t)b0 * H);
#if __has_builtin(__builtin_amdgcn_global_load_lds)
#pragma unroll
        for (int i = 0; i < 16; i++) {
            int r = i * 8 + wid;                 // 0..127 = (row, half)
            int row = r >> 1, half = r & 1;
            int m = half * 64 + lane;            // dest 16B-chunk within row
            const void* src = hrb + row * 2048 + ((m ^ (row & 7)) << 4);
            __builtin_amdgcn_global_load_lds(
                (const __attribute__((address_space(1))) void*)src,
                (__attribute__((address_space(3))) void*)(smem + row * 2048 + half * 1024),
                16, 0, 0);
        }
#else
#pragma unroll
        for (int i = 0; i < 16; i++) {
            int flat = i * 512 + tid;
            int row = flat >> 7, c16 = flat & 127;
            u32x4 v = *(const u32x4*)(hrb + (size_t)row * 2048 + c16 * 16);
            *(u32x4*)(smem + row * 2048 + ((c16 * 16) ^ ((row & 7) << 4))) = v;
        }
#endif
        __syncthreads();
    }

    f32x4 acc[4] = {};
    if (t > 0) {
        const __hip_bfloat16* wp = wF + (size_t)(d * 256 + jt * 8 + wid) * 16384;
        int brow[4], bswz[4];
#pragma unroll
        for (int bs = 0; bs < 4; bs++) {
            int row = bs * 16 + l15;
            brow[bs] = row * 2048;
            bswz[bs] = (row & 7) << 4;
        }
        bf16x8 Acur = *(const bf16x8*)(wp + lane * 8);
        bf16x8 Bcur[4];
#pragma unroll
        for (int bs = 0; bs < 4; bs++)
            Bcur[bs] = *(const bf16x8*)(smem + brow[bs] + ((l4 * 16) ^ bswz[bs]));
#pragma unroll
        for (int kk = 0; kk < 32; kk++) {
            bf16x8 A = Acur;
            bf16x8 B0 = Bcur[0], B1 = Bcur[1], B2 = Bcur[2], B3 = Bcur[3];
            if (kk < 31) {
                Acur = *(const bf16x8*)(wp + (kk + 1) * 512 + lane * 8);
                int koff = (kk + 1) * 64 + l4 * 16;
#pragma unroll
                for (int bs = 0; bs < 4; bs++)
                    Bcur[bs] = *(const bf16x8*)(smem + brow[bs] + (koff ^ bswz[bs]));
            }
            acc[0] = __builtin_amdgcn_mfma_f32_16x16x32_bf16(A, B0, acc[0], 0, 0, 0);
            acc[1] = __builtin_amdgcn_mfma_f32_16x16x32_bf16(A, B1, acc[1], 0, 0, 0);
            acc[2] = __builtin_amdgcn_mfma_f32_16x16x32_bf16(A, B2, acc[2], 0, 0, 0);
            acc[3] = __builtin_amdgcn_mfma_f32_16x16x32_bf16(A, B3, acc[3], 0, 0, 0);
        }
    }

    // proj gather for this step
    const int tt = d ? (S - 1 - t) : t;
    const int j = jt * 32 + wid * 4 + l4;
    const f32x4* pp = (const f32x4*)projP + ((size_t)d * 1024 + j) * 128;
    f32x4 pj[4];
#pragma unroll
    for (int bs = 0; bs < 4; bs++) {
        int v = x[(b0 + bs * 16 + l15) * S + tt];
        pj[bs] = pp[v];
    }

    float* cp = cws + ((size_t)bid * 512 + tid) * 4;
    f32x4 cv = {0.f, 0.f, 0.f, 0.f};
    if (t > 0) cv = *(const f32x4*)cp;

    float hnv[4];
#pragma unroll
    for (int bs = 0; bs < 4; bs++) {
        float zg = acc[bs][0] + pj[bs][0];
        float zi = acc[bs][1] + pj[bs][1];
        float zf = acc[bs][2] + pj[bs][2];
        float zo = acc[bs][3] + pj[bs][3];
        float gg = tanh_fast(zg);
        float ii = sigf(zi);
        float ff = sigf(zf);
        float oo = sigf(zo);
        float cn = gg * ii + cv[bs] * ff;
        cv[bs] = cn;
        hnv[bs] = tanh_fast(cn) * oo;
    }
    *(f32x4*)cp = cv;

    // pure-register wave transpose via shfl (verified r6-r13 pattern)
    unsigned plo = (unsigned)f2bf(hnv[0]) | ((unsigned)f2bf(hnv[1]) << 16);
    unsigned phi = (unsigned)f2bf(hnv[2]) | ((unsigned)f2bf(hnv[3]) << 16);
    unsigned short o4[4];
#pragma unroll
    for (int p = 0; p < 4; p++) {
        int src = p * 16 + l15;
        unsigned vlo = __shfl(plo, src);
        unsigned vhi = __shfl(phi, src);
        unsigned sel = (l4 < 2) ? vlo : vhi;
        o4[p] = (l4 & 1) ? (unsigned short)(sel >> 16) : (unsigned short)(sel & 0xffffu);
    }
    u64 hv = (u64)o4[0] | ((u64)o4[1] << 16) | ((u64)o4[2] << 32) | ((u64)o4[3] << 48);
    __hip_bfloat16* hw = hbuf + (size_t)((t + 1) & 1) * 2 * B * H + dBH
                         + (size_t)(b0 + lane) * H + jt * 32 + wid * 4;
    *(u64a*)hw = hv;
}

// ---- head: logits + log_softmax (reads bf16 h, parity 0) ----
__global__ void head_kernel(const __hip_bfloat16* __restrict__ hbuf,
                            const float* __restrict__ p_w,
                            const float* __restrict__ p_b,
                            float* __restrict__ out) {
    int b = blockIdx.x;
    int lane = threadIdx.x;  // 64
    float part[C];
#pragma unroll
    for (int cc = 0; cc < C; cc++) part[cc] = 0.0f;
    for (int jj = lane; jj < 2 * H; jj += 64) {
        float hv = (jj < H)
            ? __bfloat162float(hbuf[(size_t)b * H + jj])
            : __bfloat162float(hbuf[(size_t)B * H + (size_t)b * H + jj - H]);
#pragma unroll
        for (int cc = 0; cc < C; cc++) part[cc] += hv * p_w[cc * 2 * H + jj];
    }
#pragma unroll
    for (int cc = 0; cc < C; cc++) {
        float v = part[cc];
        for (int off = 32; off; off >>= 1) v += __shfl_down(v, off);
        part[cc] = v;
    }
    if (lane == 0) {
        float lg[C];
        float m = -1e30f;
        for (int cc = 0; cc < C; cc++) {
            lg[cc] = part[cc] + p_b[cc];
            m = fmaxf(m, lg[cc]);
        }
        float s = 0.0f;
        for (int cc = 0; cc < C; cc++) s += expf(lg[cc] - m);
        float lse = logf(s) + m;
        for (int cc = 0; cc < C; cc++) out[b * C + cc] = lg[cc] - lse;
    }
}

extern "C" void kernel_launch(void* const* d_in, const int* in_sizes, int n_in,
                              void* d_out, int out_size, void* d_ws, size_t ws_size,
                              hipStream_t stream) {
    const int*   x     = (const int*)d_in[0];
    const float* embed = (const float*)d_in[1];
    const float* fwd_W = (const float*)d_in[2];
    const float* fwd_b = (const float*)d_in[3];
    const float* bwd_W = (const float*)d_in[4];
    const float* bwd_b = (const float*)d_in[5];
    const float* p_w   = (const float*)d_in[6];
    const float* p_b   = (const float*)d_in[7];
    float* outp = (float*)d_out;

    char* ws = (char*)d_ws;
    __hip_bfloat16* wF  = (__hip_bfloat16*)ws;  ws += (size_t)2 * 256 * 16384 * 2;    // 16 MB
    // 8 MB region shared in time: wxF (prep only) overlays cws (steps only)
    __hip_bfloat16* wxF = (__hip_bfloat16*)ws;
    float* cws = (float*)ws;                    ws += (size_t)2 * 256 * 8192 * 2;     // 8 MB
    unsigned short* ehl = (unsigned short*)ws;  ws += (size_t)2 * 128 * 512 * 2;      // 256 KB
    float* projP = (float*)ws;                  ws += (size_t)2 * 1024 * 128 * 4 * 4; // 4 MB
    __hip_bfloat16* hbuf = (__hip_bfloat16*)ws; ws += (size_t)2 * 2 * B * H * 2;      // 2 MB

    hipLaunchKernelGGL(prep_build, dim3(6400), dim3(256), 0, stream,
                       fwd_W, bwd_W, embed, wF, wxF, ehl);

    hipFuncSetAttribute((const void*)projp_mfma,
                        hipFuncAttributeMaxDynamicSharedMemorySize, 65536);
    hipLaunchKernelGGL(projp_mfma, dim3(256), dim3(256), 65536, stream,
                       wxF, ehl, fwd_b, bwd_b, projP);

    hipFuncSetAttribute((const void*)step_kernel,
                        hipFuncAttributeMaxDynamicSharedMemorySize, LDS_H);
    for (int t = 0; t < S; t++)
        hipLaunchKernelGGL(step_kernel, dim3(256), dim3(512), LDS_H, stream,
                           x, wF, projP, hbuf, cws, t);

    hipLaunchKernelGGL(head_kernel, dim3(B), dim3(64), 0, stream,
                       hbuf, p_w, p_b, outp);
}